// Round 1
// baseline (227.492 us; speedup 1.0000x reference)
//
#include <hip/hip_runtime.h>

// CurvatureLoss: B=4, N=4096, fp32 point clouds.
// loss = mean_{b,i} (adv_kappa - ori_kappa)^2
//   ori_kappa: mean_|unitvec(ori_knn2) . ori_normal|
//   adv_kappa: mean_|unitvec(adv_knn2) . ori_normals[argmin dist(adv_i, ori)]|
//
// Layout: 256 threads/block = 32 queries x 8 candidate-chunks (512 cands each).
// grid = B * N/32 = 512 blocks. Candidate loads are broadcast (32 lanes share
// one address) -> L1-served; data (576 KB total) is L2-resident.

constexpr int BB   = 4;
constexpr int NN   = 4096;
constexpr int QPB  = 32;            // queries per block
constexpr int TPQ  = 8;             // chunks (threads) per query
constexpr int SEG  = NN / TPQ;      // 512 candidates per chunk
constexpr float FBIG = 3.402823466e+38f;

__device__ __forceinline__ float unit_absdot(const float* __restrict__ pc, int i,
                                             float px, float py, float pz,
                                             float nx, float ny, float nz) {
    float vx = pc[3 * i + 0] - px;
    float vy = pc[3 * i + 1] - py;
    float vz = pc[3 * i + 2] - pz;
    float s  = vx * vx + vy * vy + vz * vz + 1e-12f;
    float inv = 1.0f / sqrtf(s);
    return fabsf((vx * nx + vy * ny + vz * nz) * inv);
}

__global__ __launch_bounds__(256) void curv_loss_kernel(
    const float* __restrict__ ori, const float* __restrict__ adv,
    const float* __restrict__ nrm, float* __restrict__ out)
{
    const int tid    = threadIdx.x;
    const int lane_q = tid & (QPB - 1);   // 0..31: which query
    const int chunk  = tid >> 5;          // 0..7 : which candidate chunk
    const int b      = blockIdx.x >> 7;   // / (N/QPB = 128)
    const int qtile  = blockIdx.x & 127;
    const int q      = qtile * QPB + lane_q;

    const float* __restrict__ ob = ori + (size_t)b * NN * 3;
    const float* __restrict__ ab = adv + (size_t)b * NN * 3;
    const float* __restrict__ nb = nrm + (size_t)b * NN * 3;

    const float qox = ob[3 * q], qoy = ob[3 * q + 1], qoz = ob[3 * q + 2];
    const float qax = ab[3 * q], qay = ab[3 * q + 1], qaz = ab[3 * q + 2];

    // per-chunk partial results
    float od0 = FBIG, od1 = FBIG;  int oi0 = 0, oi1 = 0;   // ori-ori top2 (excl self)
    float ad0 = FBIG, ad1 = FBIG;  int ai0 = 0, ai1 = 0;   // adv-adv top2 (excl self)
    float md  = FBIG;              int mi  = 0;            // adv-ori argmin

    const int j0 = chunk * SEG;

    // pass 1: ori candidates -> ori knn + adv->ori argmin
    #pragma unroll 4
    for (int k = 0; k < SEG; ++k) {
        const int j = j0 + k;
        const float cx = ob[3 * j], cy = ob[3 * j + 1], cz = ob[3 * j + 2];
        float dx = qox - cx, dy = qoy - cy, dz = qoz - cz;
        const float doo = dx * dx + dy * dy + dz * dz;
        float ex = qax - cx, ey = qay - cy, ez = qaz - cz;
        const float dao = ex * ex + ey * ey + ez * ez;
        if (j != q) {
            if (doo < od0)      { od1 = od0; oi1 = oi0; od0 = doo; oi0 = j; }
            else if (doo < od1) { od1 = doo; oi1 = j; }
        }
        if (dao < md) { md = dao; mi = j; }
    }

    // pass 2: adv candidates -> adv knn
    #pragma unroll 4
    for (int k = 0; k < SEG; ++k) {
        const int j = j0 + k;
        const float cx = ab[3 * j], cy = ab[3 * j + 1], cz = ab[3 * j + 2];
        float ex = qax - cx, ey = qay - cy, ez = qaz - cz;
        const float daa = ex * ex + ey * ey + ez * ez;
        if (j != q) {
            if (daa < ad0)      { ad1 = ad0; ai1 = ai0; ad0 = daa; ai0 = j; }
            else if (daa < ad1) { ad1 = daa; ai1 = j; }
        }
    }

    // stage partials to LDS: [chunk][query]
    __shared__ float s_od0[TPQ][QPB], s_od1[TPQ][QPB];
    __shared__ int   s_oi0[TPQ][QPB], s_oi1[TPQ][QPB];
    __shared__ float s_ad0[TPQ][QPB], s_ad1[TPQ][QPB];
    __shared__ int   s_ai0[TPQ][QPB], s_ai1[TPQ][QPB];
    __shared__ float s_md [TPQ][QPB];
    __shared__ int   s_mi [TPQ][QPB];

    s_od0[chunk][lane_q] = od0;  s_od1[chunk][lane_q] = od1;
    s_oi0[chunk][lane_q] = oi0;  s_oi1[chunk][lane_q] = oi1;
    s_ad0[chunk][lane_q] = ad0;  s_ad1[chunk][lane_q] = ad1;
    s_ai0[chunk][lane_q] = ai0;  s_ai1[chunk][lane_q] = ai1;
    s_md [chunk][lane_q] = md;   s_mi [chunk][lane_q] = mi;
    __syncthreads();

    if (tid < QPB) {
        // merge the 8 chunk-partials for query q (= qtile*32 + tid; registers
        // qox.. already hold this query's coords since lane_q == tid here).
        float bo0 = FBIG, bo1 = FBIG;  int bio0 = 0, bio1 = 0;
        float ba0 = FBIG, ba1 = FBIG;  int bia0 = 0, bia1 = 0;
        float bmd = FBIG;              int bmi  = 0;
        #pragma unroll
        for (int c = 0; c < TPQ; ++c) {
            // ascending chunk order + strict < keeps smaller-index ties first
            float d; int i;
            d = s_od0[c][tid]; i = s_oi0[c][tid];
            if (d < bo0)      { bo1 = bo0; bio1 = bio0; bo0 = d; bio0 = i; }
            else if (d < bo1) { bo1 = d; bio1 = i; }
            d = s_od1[c][tid]; i = s_oi1[c][tid];
            if (d < bo0)      { bo1 = bo0; bio1 = bio0; bo0 = d; bio0 = i; }
            else if (d < bo1) { bo1 = d; bio1 = i; }
            d = s_ad0[c][tid]; i = s_ai0[c][tid];
            if (d < ba0)      { ba1 = ba0; bia1 = bia0; ba0 = d; bia0 = i; }
            else if (d < ba1) { ba1 = d; bia1 = i; }
            d = s_ad1[c][tid]; i = s_ai1[c][tid];
            if (d < ba0)      { ba1 = ba0; bia1 = bia0; ba0 = d; bia0 = i; }
            else if (d < ba1) { ba1 = d; bia1 = i; }
            d = s_md[c][tid];
            if (d < bmd) { bmd = d; bmi = s_mi[c][tid]; }
        }

        // ori kappa: unit vectors to 2 nearest ori neighbors . own normal
        const float nx = nb[3 * q], ny = nb[3 * q + 1], nz = nb[3 * q + 2];
        const float ok = 0.5f * (unit_absdot(ob, bio0, qox, qoy, qoz, nx, ny, nz) +
                                 unit_absdot(ob, bio1, qox, qoy, qoz, nx, ny, nz));

        // adv kappa: normal taken from nearest ori point
        const float anx = nb[3 * bmi], any_ = nb[3 * bmi + 1], anz = nb[3 * bmi + 2];
        const float ak = 0.5f * (unit_absdot(ab, bia0, qax, qay, qaz, anx, any_, anz) +
                                 unit_absdot(ab, bia1, qax, qay, qaz, anx, any_, anz));

        const float diff = ak - ok;
        float val = diff * diff;

        // reduce lanes 0..31 of wave 0
        #pragma unroll
        for (int off = 16; off > 0; off >>= 1)
            val += __shfl_down(val, off);
        if (tid == 0)
            atomicAdd(out, val * (1.0f / (float)(BB * NN)));
    }
}

extern "C" void kernel_launch(void* const* d_in, const int* in_sizes, int n_in,
                              void* d_out, int out_size, void* d_ws, size_t ws_size,
                              hipStream_t stream) {
    const float* ori = (const float*)d_in[0];
    const float* adv = (const float*)d_in[1];
    const float* nrm = (const float*)d_in[2];
    float* out = (float*)d_out;

    // harness poisons d_out to 0xAA before every timed launch -> zero it
    hipMemsetAsync(out, 0, sizeof(float), stream);

    dim3 grid(BB * (NN / QPB));   // 512 blocks
    dim3 block(QPB * TPQ);        // 256 threads
    hipLaunchKernelGGL(curv_loss_kernel, grid, block, 0, stream,
                       ori, adv, nrm, out);
}

// Round 2
// 154.082 us; speedup vs baseline: 1.4764x; 1.4764x over previous
//
#include <hip/hip_runtime.h>

// CurvatureLoss: B=4, N=4096, fp32.
// R2: occupancy was the bottleneck (22% occ, 48% VALUBusy, grid cap 25%).
//  - QPB=8, TPQ=32 -> 2048 blocks x 4 waves = 8192 waves = 100% occ cap.
//  - Pre-pack points as float4{x,y,z,|c|^2} in d_ws; hot loop uses key
//    cc - 2*q.c (monotone in distance per query): 1 dwordx4 load + 4 FMA
//    per distance instead of 3 loads + 6 ALU.

constexpr int BB   = 4;
constexpr int NN   = 4096;
constexpr int QPB  = 8;             // queries per block
constexpr int TPQ  = 32;            // chunks (threads) per query
constexpr int SEG  = NN / TPQ;      // 128 candidates per chunk
constexpr float FBIG = 3.402823466e+38f;

__global__ __launch_bounds__(256) void pack_kernel(
    const float* __restrict__ ori, const float* __restrict__ adv,
    float4* __restrict__ oriP, float4* __restrict__ advP)
{
    const int i = blockIdx.x * blockDim.x + threadIdx.x;
    if (i < BB * NN) {
        float x = ori[3 * i], y = ori[3 * i + 1], z = ori[3 * i + 2];
        oriP[i] = make_float4(x, y, z, x * x + y * y + z * z);
        x = adv[3 * i]; y = adv[3 * i + 1]; z = adv[3 * i + 2];
        advP[i] = make_float4(x, y, z, x * x + y * y + z * z);
    }
}

__device__ __forceinline__ float unit_absdot4(const float4* __restrict__ pc, int i,
                                              float px, float py, float pz,
                                              float nx, float ny, float nz) {
    const float4 c = pc[i];
    const float vx = c.x - px, vy = c.y - py, vz = c.z - pz;
    const float s  = vx * vx + vy * vy + vz * vz + 1e-12f;
    return fabsf((vx * nx + vy * ny + vz * nz) * (1.0f / sqrtf(s)));
}

__global__ __launch_bounds__(256) void curv_loss_kernel(
    const float4* __restrict__ oriP, const float4* __restrict__ advP,
    const float* __restrict__ nrm, float* __restrict__ out)
{
    const int tid    = threadIdx.x;
    const int lane_q = tid & (QPB - 1);    // 0..7 : which query
    const int chunk  = tid >> 3;           // 0..31: which candidate chunk
    const int b      = blockIdx.x >> 9;    // / (N/QPB = 512)
    const int qtile  = blockIdx.x & 511;
    const int q      = qtile * QPB + lane_q;

    const float4* __restrict__ ob = oriP + (size_t)b * NN;
    const float4* __restrict__ ab = advP + (size_t)b * NN;
    const float*  __restrict__ nb = nrm  + (size_t)b * NN * 3;

    const float4 qo = ob[q];
    const float4 qa = ab[q];

    // per-chunk partials (keys are cc - 2*q.c : monotone in true distance)
    float od0 = FBIG, od1 = FBIG;  int oi0 = 0, oi1 = 0;   // ori-ori top2 (excl self)
    float ad0 = FBIG, ad1 = FBIG;  int ai0 = 0, ai1 = 0;   // adv-adv top2 (excl self)
    float md  = FBIG;              int mi  = 0;            // adv->ori argmin

    const int j0 = chunk * SEG;

    // pass 1: ori candidates -> ori knn key + adv->ori argmin key
    #pragma unroll 4
    for (int k = 0; k < SEG; ++k) {
        const int j = j0 + k;
        const float4 c = ob[j];
        const float to  = qo.x * c.x + qo.y * c.y + qo.z * c.z;
        const float doo = fmaf(-2.0f, to, c.w);
        const float ta  = qa.x * c.x + qa.y * c.y + qa.z * c.z;
        const float dao = fmaf(-2.0f, ta, c.w);
        if (j != q) {
            if (doo < od0)      { od1 = od0; oi1 = oi0; od0 = doo; oi0 = j; }
            else if (doo < od1) { od1 = doo; oi1 = j; }
        }
        if (dao < md) { md = dao; mi = j; }
    }

    // pass 2: adv candidates -> adv knn key
    #pragma unroll 4
    for (int k = 0; k < SEG; ++k) {
        const int j = j0 + k;
        const float4 c = ab[j];
        const float ta  = qa.x * c.x + qa.y * c.y + qa.z * c.z;
        const float daa = fmaf(-2.0f, ta, c.w);
        if (j != q) {
            if (daa < ad0)      { ad1 = ad0; ai1 = ai0; ad0 = daa; ai0 = j; }
            else if (daa < ad1) { ad1 = daa; ai1 = j; }
        }
    }

    // stage partials to LDS: [chunk][query]
    __shared__ float s_od0[TPQ][QPB], s_od1[TPQ][QPB];
    __shared__ int   s_oi0[TPQ][QPB], s_oi1[TPQ][QPB];
    __shared__ float s_ad0[TPQ][QPB], s_ad1[TPQ][QPB];
    __shared__ int   s_ai0[TPQ][QPB], s_ai1[TPQ][QPB];
    __shared__ float s_md [TPQ][QPB];
    __shared__ int   s_mi [TPQ][QPB];

    s_od0[chunk][lane_q] = od0;  s_od1[chunk][lane_q] = od1;
    s_oi0[chunk][lane_q] = oi0;  s_oi1[chunk][lane_q] = oi1;
    s_ad0[chunk][lane_q] = ad0;  s_ad1[chunk][lane_q] = ad1;
    s_ai0[chunk][lane_q] = ai0;  s_ai1[chunk][lane_q] = ai1;
    s_md [chunk][lane_q] = md;   s_mi [chunk][lane_q] = mi;
    __syncthreads();

    if (tid < QPB) {
        // merge 32 chunk-partials for query q (lane_q == tid here, so qo/qa
        // registers already hold this query's coords).
        float bo0 = FBIG, bo1 = FBIG;  int bio0 = 0, bio1 = 0;
        float ba0 = FBIG, ba1 = FBIG;  int bia0 = 0, bia1 = 0;
        float bmd = FBIG;              int bmi  = 0;
        #pragma unroll
        for (int c = 0; c < TPQ; ++c) {
            // ascending chunk order + strict < keeps smaller-index ties first
            float d; int i;
            d = s_od0[c][tid]; i = s_oi0[c][tid];
            if (d < bo0)      { bo1 = bo0; bio1 = bio0; bo0 = d; bio0 = i; }
            else if (d < bo1) { bo1 = d; bio1 = i; }
            d = s_od1[c][tid]; i = s_oi1[c][tid];
            if (d < bo0)      { bo1 = bo0; bio1 = bio0; bo0 = d; bio0 = i; }
            else if (d < bo1) { bo1 = d; bio1 = i; }
            d = s_ad0[c][tid]; i = s_ai0[c][tid];
            if (d < ba0)      { ba1 = ba0; bia1 = bia0; ba0 = d; bia0 = i; }
            else if (d < ba1) { ba1 = d; bia1 = i; }
            d = s_ad1[c][tid]; i = s_ai1[c][tid];
            if (d < ba0)      { ba1 = ba0; bia1 = bia0; ba0 = d; bia0 = i; }
            else if (d < ba1) { ba1 = d; bia1 = i; }
            d = s_md[c][tid];
            if (d < bmd) { bmd = d; bmi = s_mi[c][tid]; }
        }

        // ori kappa: unit vectors to 2 nearest ori neighbors . own normal
        const float nx = nb[3 * q], ny = nb[3 * q + 1], nz = nb[3 * q + 2];
        const float ok = 0.5f * (unit_absdot4(ob, bio0, qo.x, qo.y, qo.z, nx, ny, nz) +
                                 unit_absdot4(ob, bio1, qo.x, qo.y, qo.z, nx, ny, nz));

        // adv kappa: normal taken from nearest ori point
        const float anx = nb[3 * bmi], any_ = nb[3 * bmi + 1], anz = nb[3 * bmi + 2];
        const float ak = 0.5f * (unit_absdot4(ab, bia0, qa.x, qa.y, qa.z, anx, any_, anz) +
                                 unit_absdot4(ab, bia1, qa.x, qa.y, qa.z, anx, any_, anz));

        const float diff = ak - ok;
        float val = diff * diff;

        // reduce lanes 0..7 of wave 0
        #pragma unroll
        for (int off = QPB / 2; off > 0; off >>= 1)
            val += __shfl_down(val, off);
        if (tid == 0)
            atomicAdd(out, val * (1.0f / (float)(BB * NN)));
    }
}

extern "C" void kernel_launch(void* const* d_in, const int* in_sizes, int n_in,
                              void* d_out, int out_size, void* d_ws, size_t ws_size,
                              hipStream_t stream) {
    const float* ori = (const float*)d_in[0];
    const float* adv = (const float*)d_in[1];
    const float* nrm = (const float*)d_in[2];
    float* out = (float*)d_out;

    float4* oriP = (float4*)d_ws;                 // B*N float4 = 256 KB
    float4* advP = oriP + (size_t)BB * NN;        // + 256 KB

    // harness poisons d_out/d_ws to 0xAA before every timed launch
    hipMemsetAsync(out, 0, sizeof(float), stream);

    hipLaunchKernelGGL(pack_kernel, dim3((BB * NN + 255) / 256), dim3(256), 0, stream,
                       ori, adv, oriP, advP);

    dim3 grid(BB * (NN / QPB));   // 2048 blocks
    dim3 block(QPB * TPQ);        // 256 threads
    hipLaunchKernelGGL(curv_loss_kernel, grid, block, 0, stream,
                       oriP, advP, nrm, out);
}

// Round 3
// 137.286 us; speedup vs baseline: 1.6571x; 1.1223x over previous
//
#include <hip/hip_runtime.h>

// CurvatureLoss: B=4, N=4096, fp32.
// R3: VALU-issue-bound (80% VALUBusy). Cut ops/candidate ~35 -> ~25:
//  - key' = q.c - 0.5|c|^2 (pack w=0.5|c|^2): one 3-FMA chain per key;
//    LARGER key = closer, so selection is max-top2.
//  - index embedded in low 7 mantissa bits (local step k, 128 steps) as
//    (127-k): top-2 via pure v_min/v_max, no cndmask index chains.
//    Perturbation ~3e-5 abs vs NN gaps ~6e-3 -> rare tie flips, each
//    ~5e-6 on the loss (threshold 5.8e-4).
//  - interleaved chunking j = 32k + chunk: wave reads contiguous 128B/step.
//  - both passes fused into one loop (ori + adv candidate per step).

constexpr int BB  = 4;
constexpr int NN  = 4096;
constexpr int QPB = 8;            // queries per block
constexpr int CPB = 32;           // chunks per query (threads)
constexpr int NK  = NN / CPB;     // 128 steps; candidate j = CPB*k + chunk
constexpr float NEGBIG = -3.402823466e+38f;

__global__ __launch_bounds__(256) void pack_kernel(
    const float* __restrict__ ori, const float* __restrict__ adv,
    float4* __restrict__ oriP, float4* __restrict__ advP)
{
    const int i = blockIdx.x * blockDim.x + threadIdx.x;
    if (i < BB * NN) {
        float x = ori[3 * i], y = ori[3 * i + 1], z = ori[3 * i + 2];
        oriP[i] = make_float4(x, y, z, 0.5f * (x * x + y * y + z * z));
        x = adv[3 * i]; y = adv[3 * i + 1]; z = adv[3 * i + 2];
        advP[i] = make_float4(x, y, z, 0.5f * (x * x + y * y + z * z));
    }
}

__device__ __forceinline__ float unit_absdot4(const float4* __restrict__ pc, int i,
                                              float px, float py, float pz,
                                              float nx, float ny, float nz) {
    const float4 c = pc[i];
    const float vx = c.x - px, vy = c.y - py, vz = c.z - pz;
    const float s  = vx * vx + vy * vy + vz * vz + 1e-12f;
    return fabsf((vx * nx + vy * ny + vz * nz) * (1.0f / sqrtf(s)));
}

__device__ __forceinline__ float embed(float t, unsigned eb) {
    return __uint_as_float((__float_as_uint(t) & 0xFFFFFF80u) | eb);
}

__global__ __launch_bounds__(256, 8) void curv_loss_kernel(
    const float4* __restrict__ oriP, const float4* __restrict__ advP,
    const float* __restrict__ nrm, float* __restrict__ out)
{
    const int tid = threadIdx.x;
    const int lq  = tid & (QPB - 1);    // 0..7 : query within tile
    const int ch  = tid >> 3;           // 0..31: chunk
    const int b   = blockIdx.x >> 9;    // / (N/QPB = 512)
    const int qt  = blockIdx.x & 511;
    const int q   = qt * QPB + lq;

    const float4* __restrict__ ob = oriP + (size_t)b * NN;
    const float4* __restrict__ ab = advP + (size_t)b * NN;
    const float*  __restrict__ nb = nrm  + (size_t)b * NN * 3;

    const float4 qo = ob[q];
    const float4 qa = ab[q];

    // self (j == q) lives in this chunk iff ch == q%32, at step k = q/32
    const int kself = (ch == (q & (CPB - 1))) ? (q >> 5) : NK;

    // max-top2 of embedded keys (larger = closer); md = argmax for adv->ori
    float od0 = NEGBIG, od1 = NEGBIG;
    float ad0 = NEGBIG, ad1 = NEGBIG;
    float md  = NEGBIG;

    const float4* __restrict__ op = ob + ch;
    const float4* __restrict__ ap = ab + ch;

    #pragma unroll 4
    for (int k = 0; k < NK; ++k) {
        const float4 co = op[k * CPB];
        const float4 ca = ap[k * CPB];
        const unsigned eb = (unsigned)(NK - 1 - k);  // smaller index -> larger key

        float t;
        t = fmaf(qo.z, co.z, -co.w); t = fmaf(qo.y, co.y, t); t = fmaf(qo.x, co.x, t);
        float ko = embed(t, eb);                       // ori-ori
        t = fmaf(qa.z, co.z, -co.w); t = fmaf(qa.y, co.y, t); t = fmaf(qa.x, co.x, t);
        float km = embed(t, eb);                       // adv->ori (no self excl.)
        t = fmaf(qa.z, ca.z, -ca.w); t = fmaf(qa.y, ca.y, t); t = fmaf(qa.x, ca.x, t);
        float ka = embed(t, eb);                       // adv-adv

        const bool self = (k == kself);
        ko = self ? NEGBIG : ko;
        ka = self ? NEGBIG : ka;

        od1 = fmaxf(od1, fminf(od0, ko));
        od0 = fmaxf(od0, ko);
        md  = fmaxf(md, km);
        ad1 = fmaxf(ad1, fminf(ad0, ka));
        ad0 = fmaxf(ad0, ka);
    }

    __shared__ float s_od0[CPB][QPB], s_od1[CPB][QPB];
    __shared__ float s_ad0[CPB][QPB], s_ad1[CPB][QPB];
    __shared__ float s_md [CPB][QPB];

    s_od0[ch][lq] = od0;  s_od1[ch][lq] = od1;
    s_ad0[ch][lq] = ad0;  s_ad1[ch][lq] = ad1;
    s_md [ch][lq] = md;
    __syncthreads();

    if (tid < QPB) {
        // merge 32 chunk-partials for query q (lq == tid; qo/qa valid).
        float bo0 = NEGBIG, bo1 = NEGBIG;  int bio0 = 0, bio1 = 0;
        float ba0 = NEGBIG, ba1 = NEGBIG;  int bia0 = 0, bia1 = 0;
        float bmd = NEGBIG;                int bmi  = 0;
        #pragma unroll
        for (int c = 0; c < CPB; ++c) {
            // ascending chunk + strict > : ties keep smaller global index
            float d; int i;
            d = s_od0[c][tid];
            i = ((NK - 1 - (int)(__float_as_uint(d) & 0x7Fu)) << 5) | c;
            if (d > bo0)      { bo1 = bo0; bio1 = bio0; bo0 = d; bio0 = i; }
            else if (d > bo1) { bo1 = d; bio1 = i; }
            d = s_od1[c][tid];
            i = ((NK - 1 - (int)(__float_as_uint(d) & 0x7Fu)) << 5) | c;
            if (d > bo0)      { bo1 = bo0; bio1 = bio0; bo0 = d; bio0 = i; }
            else if (d > bo1) { bo1 = d; bio1 = i; }
            d = s_ad0[c][tid];
            i = ((NK - 1 - (int)(__float_as_uint(d) & 0x7Fu)) << 5) | c;
            if (d > ba0)      { ba1 = ba0; bia1 = bia0; ba0 = d; bia0 = i; }
            else if (d > ba1) { ba1 = d; bia1 = i; }
            d = s_ad1[c][tid];
            i = ((NK - 1 - (int)(__float_as_uint(d) & 0x7Fu)) << 5) | c;
            if (d > ba0)      { ba1 = ba0; bia1 = bia0; ba0 = d; bia0 = i; }
            else if (d > ba1) { ba1 = d; bia1 = i; }
            d = s_md[c][tid];
            if (d > bmd) {
                bmd = d;
                bmi = ((NK - 1 - (int)(__float_as_uint(d) & 0x7Fu)) << 5) | c;
            }
        }

        // ori kappa: unit vectors to 2 nearest ori neighbors . own normal
        const float nx = nb[3 * q], ny = nb[3 * q + 1], nz = nb[3 * q + 2];
        const float ok = 0.5f * (unit_absdot4(ob, bio0, qo.x, qo.y, qo.z, nx, ny, nz) +
                                 unit_absdot4(ob, bio1, qo.x, qo.y, qo.z, nx, ny, nz));

        // adv kappa: normal of nearest ori point
        const float anx = nb[3 * bmi], any_ = nb[3 * bmi + 1], anz = nb[3 * bmi + 2];
        const float ak = 0.5f * (unit_absdot4(ab, bia0, qa.x, qa.y, qa.z, anx, any_, anz) +
                                 unit_absdot4(ab, bia1, qa.x, qa.y, qa.z, anx, any_, anz));

        const float diff = ak - ok;
        float val = diff * diff;

        #pragma unroll
        for (int off = QPB / 2; off > 0; off >>= 1)
            val += __shfl_down(val, off);
        if (tid == 0)
            atomicAdd(out, val * (1.0f / (float)(BB * NN)));
    }
}

extern "C" void kernel_launch(void* const* d_in, const int* in_sizes, int n_in,
                              void* d_out, int out_size, void* d_ws, size_t ws_size,
                              hipStream_t stream) {
    const float* ori = (const float*)d_in[0];
    const float* adv = (const float*)d_in[1];
    const float* nrm = (const float*)d_in[2];
    float* out = (float*)d_out;

    float4* oriP = (float4*)d_ws;                 // 256 KB
    float4* advP = oriP + (size_t)BB * NN;        // 256 KB

    hipMemsetAsync(out, 0, sizeof(float), stream);

    hipLaunchKernelGGL(pack_kernel, dim3((BB * NN + 255) / 256), dim3(256), 0, stream,
                       ori, adv, oriP, advP);

    dim3 grid(BB * (NN / QPB));   // 2048 blocks
    dim3 block(QPB * CPB);        // 256 threads
    hipLaunchKernelGGL(curv_loss_kernel, grid, block, 0, stream,
                       oriP, advP, nrm, out);
}

// Round 4
// 106.355 us; speedup vs baseline: 2.1390x; 1.2908x over previous
//
#include <hip/hip_runtime.h>

// CurvatureLoss: B=4, N=4096, fp32.
// R4: latency/structure-bound (VALUBusy 58%, occ 52%). Restructure:
//  - 2 queries per thread, wave = 64 chunks -> coalesced 16B/lane loads,
//    2 loads serve 6 keys/step (was 3), 6 independent FMA chains.
//  - butterfly __shfl_xor top2-merge (no LDS serial tail); index recovered
//    via __ballot match on saved per-lane partials (j = 64k + lane, lowest
//    lane wins -> smaller-index tie-break preserved).
//  - per-block partial -> d_ws, 1-block reduce kernel (kills the 2048
//    same-address atomic burst). Atomic fallback if ws_size too small.
//  - embed now 6 bits (NK=64): half R3's key perturbation.

constexpr int BB   = 4;
constexpr int NN   = 4096;
constexpr int QPB  = 8;              // queries per block (4 waves x 2)
constexpr int CPB  = 64;             // chunks = lanes per wave
constexpr int NK   = NN / CPB;       // 64 steps; candidate j = 64*k + lane
constexpr int NBLK = BB * NN / QPB;  // 2048 blocks
constexpr float NEGBIG = -3.402823466e+38f;

__global__ __launch_bounds__(256) void pack_kernel(
    const float* __restrict__ ori, const float* __restrict__ adv,
    float4* __restrict__ oriP, float4* __restrict__ advP)
{
    const int i = blockIdx.x * blockDim.x + threadIdx.x;
    if (i < BB * NN) {
        float x = ori[3 * i], y = ori[3 * i + 1], z = ori[3 * i + 2];
        oriP[i] = make_float4(x, y, z, 0.5f * (x * x + y * y + z * z));
        x = adv[3 * i]; y = adv[3 * i + 1]; z = adv[3 * i + 2];
        advP[i] = make_float4(x, y, z, 0.5f * (x * x + y * y + z * z));
    }
}

__device__ __forceinline__ float embed6(float t, unsigned eb) {
    return __uint_as_float((__float_as_uint(t) & 0xFFFFFFC0u) | eb);
}

// v is a merged key; p0/p1 are this lane's saved partials. All lanes call;
// result is wave-uniform. Lowest matching lane = lowest chunk = smallest j.
__device__ __forceinline__ int recover_j(float v, float p0, float p1) {
    unsigned long long m = __ballot((p0 == v) || (p1 == v));
    const int lane = (int)__ffsll(m) - 1;
    const int k = (NK - 1) - (int)(__float_as_uint(v) & (unsigned)(NK - 1));
    return (k << 6) | lane;
}

__device__ __forceinline__ float unit_absdot4(const float4* __restrict__ pc, int i,
                                              float px, float py, float pz,
                                              float nx, float ny, float nz) {
    const float4 c = pc[i];
    const float vx = c.x - px, vy = c.y - py, vz = c.z - pz;
    const float s  = vx * vx + vy * vy + vz * vz + 1e-12f;
    return fabsf((vx * nx + vy * ny + vz * nz) * (1.0f / sqrtf(s)));
}

__global__ __launch_bounds__(256, 8) void knn_kernel(
    const float4* __restrict__ oriP, const float4* __restrict__ advP,
    const float* __restrict__ nrm, float* __restrict__ partial,
    float* __restrict__ out, int use_partial)
{
    const int tid = threadIdx.x;
    const int ch  = tid & 63;          // chunk = lane
    const int qs  = tid >> 6;          // wave id 0..3
    const int b   = blockIdx.x >> 9;   // / (N/QPB = 512)
    const int qt  = blockIdx.x & 511;
    const int q0  = qt * QPB + qs * 2;
    const int q1  = q0 + 1;

    const float4* __restrict__ ob = oriP + (size_t)b * NN;
    const float4* __restrict__ ab = advP + (size_t)b * NN;
    const float*  __restrict__ nb = nrm  + (size_t)b * NN * 3;

    const float4 qo0 = ob[q0], qo1 = ob[q1];
    const float4 qa0 = ab[q0], qa1 = ab[q1];

    // self j==q lives at lane q&63, step q>>6
    const int ks0 = ((q0 & 63) == ch) ? (q0 >> 6) : NK;
    const int ks1 = ((q1 & 63) == ch) ? (q1 >> 6) : NK;

    float oA0 = NEGBIG, oB0 = NEGBIG;   // q0 ori-ori top2 (max = closest)
    float oA1 = NEGBIG, oB1 = NEGBIG;   // q1 ori-ori top2
    float aA0 = NEGBIG, aB0 = NEGBIG;   // q0 adv-adv top2
    float aA1 = NEGBIG, aB1 = NEGBIG;   // q1 adv-adv top2
    float m0  = NEGBIG, m1  = NEGBIG;   // adv->ori argmax (no self excl.)

    const float4* __restrict__ op = ob + ch;
    const float4* __restrict__ ap = ab + ch;

    #pragma unroll 4
    for (int k = 0; k < NK; ++k) {
        const float4 co = op[k * CPB];
        const float4 ca = ap[k * CPB];
        const unsigned eb = (unsigned)(NK - 1 - k);  // smaller index -> larger key

        float t;
        t = fmaf(qo0.z, co.z, -co.w); t = fmaf(qo0.y, co.y, t); t = fmaf(qo0.x, co.x, t);
        float ko0 = embed6(t, eb);
        t = fmaf(qo1.z, co.z, -co.w); t = fmaf(qo1.y, co.y, t); t = fmaf(qo1.x, co.x, t);
        float ko1 = embed6(t, eb);
        t = fmaf(qa0.z, co.z, -co.w); t = fmaf(qa0.y, co.y, t); t = fmaf(qa0.x, co.x, t);
        float km0 = embed6(t, eb);
        t = fmaf(qa1.z, co.z, -co.w); t = fmaf(qa1.y, co.y, t); t = fmaf(qa1.x, co.x, t);
        float km1 = embed6(t, eb);
        t = fmaf(qa0.z, ca.z, -ca.w); t = fmaf(qa0.y, ca.y, t); t = fmaf(qa0.x, ca.x, t);
        float ka0 = embed6(t, eb);
        t = fmaf(qa1.z, ca.z, -ca.w); t = fmaf(qa1.y, ca.y, t); t = fmaf(qa1.x, ca.x, t);
        float ka1 = embed6(t, eb);

        if (k == ks0) { ko0 = NEGBIG; ka0 = NEGBIG; }   // -> cndmask
        if (k == ks1) { ko1 = NEGBIG; ka1 = NEGBIG; }

        oB0 = fmaxf(oB0, fminf(oA0, ko0)); oA0 = fmaxf(oA0, ko0);
        oB1 = fmaxf(oB1, fminf(oA1, ko1)); oA1 = fmaxf(oA1, ko1);
        aB0 = fmaxf(aB0, fminf(aA0, ka0)); aA0 = fmaxf(aA0, ka0);
        aB1 = fmaxf(aB1, fminf(aA1, ka1)); aA1 = fmaxf(aA1, ka1);
        m0  = fmaxf(m0, km0);
        m1  = fmaxf(m1, km1);
    }

    // save per-lane partials for index recovery
    const float soA0 = oA0, soB0 = oB0, soA1 = oA1, soB1 = oB1;
    const float saA0 = aA0, saB0 = aB0, saA1 = aA1, saB1 = aB1;
    const float sm0 = m0, sm1 = m1;

    // wave butterfly merge: top2 (a0>=a1, b0>=b1):
    //   m0 = max(a0,b0); m1 = max(min(a0,b0), max(a1,b1))
    #pragma unroll
    for (int off = 1; off < 64; off <<= 1) {
        float r0, r1, mn;
        r0 = __shfl_xor(oA0, off); r1 = __shfl_xor(oB0, off);
        mn = fminf(oA0, r0); oA0 = fmaxf(oA0, r0); oB0 = fmaxf(mn, fmaxf(oB0, r1));
        r0 = __shfl_xor(oA1, off); r1 = __shfl_xor(oB1, off);
        mn = fminf(oA1, r0); oA1 = fmaxf(oA1, r0); oB1 = fmaxf(mn, fmaxf(oB1, r1));
        r0 = __shfl_xor(aA0, off); r1 = __shfl_xor(aB0, off);
        mn = fminf(aA0, r0); aA0 = fmaxf(aA0, r0); aB0 = fmaxf(mn, fmaxf(aB0, r1));
        r0 = __shfl_xor(aA1, off); r1 = __shfl_xor(aB1, off);
        mn = fminf(aA1, r0); aA1 = fmaxf(aA1, r0); aB1 = fmaxf(mn, fmaxf(aB1, r1));
        m0 = fmaxf(m0, __shfl_xor(m0, off));
        m1 = fmaxf(m1, __shfl_xor(m1, off));
    }

    // recover global candidate indices (wave-uniform)
    const int jo0_0 = recover_j(oA0, soA0, soB0);
    const int jo1_0 = recover_j(oB0, soA0, soB0);
    const int jo0_1 = recover_j(oA1, soA1, soB1);
    const int jo1_1 = recover_j(oB1, soA1, soB1);
    const int ja0_0 = recover_j(aA0, saA0, saB0);
    const int ja1_0 = recover_j(aB0, saA0, saB0);
    const int ja0_1 = recover_j(aA1, saA1, saB1);
    const int ja1_1 = recover_j(aB1, saA1, saB1);
    const int jm_0  = recover_j(m0, sm0, sm0);
    const int jm_1  = recover_j(m1, sm1, sm1);

    float val = 0.0f;
    if (ch < 2) {                       // lane0 -> q0, lane1 -> q1
        const int    q  = ch ? q1 : q0;
        const float4 qo = ch ? qo1 : qo0;
        const float4 qa = ch ? qa1 : qa0;
        const int io0 = ch ? jo0_1 : jo0_0;
        const int io1 = ch ? jo1_1 : jo1_0;
        const int ia0 = ch ? ja0_1 : ja0_0;
        const int ia1 = ch ? ja1_1 : ja1_0;
        const int im  = ch ? jm_1  : jm_0;

        const float nx = nb[3 * q], ny = nb[3 * q + 1], nz = nb[3 * q + 2];
        const float ok = 0.5f * (unit_absdot4(ob, io0, qo.x, qo.y, qo.z, nx, ny, nz) +
                                 unit_absdot4(ob, io1, qo.x, qo.y, qo.z, nx, ny, nz));
        const float ax = nb[3 * im], ay = nb[3 * im + 1], az = nb[3 * im + 2];
        const float ak = 0.5f * (unit_absdot4(ab, ia0, qa.x, qa.y, qa.z, ax, ay, az) +
                                 unit_absdot4(ab, ia1, qa.x, qa.y, qa.z, ax, ay, az));
        const float d = ak - ok;
        val = d * d;
    }
    val += __shfl_down(val, 1);         // lane0: q0 + q1

    __shared__ float sval[4];
    if (ch == 0) sval[qs] = val;
    __syncthreads();
    if (tid == 0) {
        const float s = sval[0] + sval[1] + sval[2] + sval[3];
        if (use_partial) partial[blockIdx.x] = s;
        else             atomicAdd(out, s * (1.0f / (float)(BB * NN)));
    }
}

__global__ __launch_bounds__(256) void reduce_kernel(
    const float* __restrict__ partial, float* __restrict__ out)
{
    const int tid = threadIdx.x;
    float s = 0.0f;
    #pragma unroll
    for (int i = tid; i < NBLK; i += 256) s += partial[i];
    #pragma unroll
    for (int off = 32; off > 0; off >>= 1) s += __shfl_down(s, off);
    __shared__ float ls[4];
    if ((tid & 63) == 0) ls[tid >> 6] = s;
    __syncthreads();
    if (tid == 0)
        out[0] = (ls[0] + ls[1] + ls[2] + ls[3]) * (1.0f / (float)(BB * NN));
}

extern "C" void kernel_launch(void* const* d_in, const int* in_sizes, int n_in,
                              void* d_out, int out_size, void* d_ws, size_t ws_size,
                              hipStream_t stream) {
    const float* ori = (const float*)d_in[0];
    const float* adv = (const float*)d_in[1];
    const float* nrm = (const float*)d_in[2];
    float* out = (float*)d_out;

    float4* oriP = (float4*)d_ws;                    // 256 KB
    float4* advP = oriP + (size_t)BB * NN;           // 256 KB
    float*  part = (float*)(advP + (size_t)BB * NN); // 8 KB
    const size_t need = (size_t)2 * BB * NN * sizeof(float4) + NBLK * sizeof(float);
    const int use_partial = (ws_size >= need) ? 1 : 0;

    if (!use_partial)
        hipMemsetAsync(out, 0, sizeof(float), stream);

    hipLaunchKernelGGL(pack_kernel, dim3((BB * NN + 255) / 256), dim3(256), 0, stream,
                       ori, adv, oriP, advP);
    hipLaunchKernelGGL(knn_kernel, dim3(NBLK), dim3(256), 0, stream,
                       oriP, advP, nrm, part, out, use_partial);
    if (use_partial)
        hipLaunchKernelGGL(reduce_kernel, dim3(1), dim3(256), 0, stream, part, out);
}